// Round 5
// baseline (44.514 us; speedup 1.0000x reference)
//
#include <hip/hip_runtime.h>
#include <hip/hip_bf16.h>

#define B_ 4
#define T_ 800
#define U_ 150
#define D_ 512
#define H_ 256
#define PADH2 132   // 132 % 32 == 4 -> worst LDS aliasing 2-way (free)

static constexpr float ARG_SCALE = 2.8853900817779268f; // 2/ln2: tanh(x)=1-2/(1+2^(c*x))
static constexpr float LOG2E_F   = 1.4426950408889634f;

typedef __attribute__((ext_vector_type(8))) short bf16x8;   // 8 bf16 in 4 VGPRs
typedef __attribute__((ext_vector_type(4))) float f32x4;

extern "C" __device__ float __ocml_exp2_f32(float);

__device__ __forceinline__ float fast_exp2(float x) {
#if __has_builtin(__builtin_amdgcn_exp2f)
    return __builtin_amdgcn_exp2f(x);
#else
    return __ocml_exp2_f32(x);
#endif
}
__device__ __forceinline__ float fast_rcp(float x) {
#if __has_builtin(__builtin_amdgcn_rcpf)
    return __builtin_amdgcn_rcpf(x);
#else
    return 1.0f / x;
#endif
}

// round-to-nearest-even fp32 -> bf16 hi, residual lo
__device__ __forceinline__ void bf16split(float x, unsigned short& hi, unsigned short& lo) {
    unsigned u = __builtin_bit_cast(unsigned, x);
    unsigned r = (u + 0x7FFFu + ((u >> 16) & 1u)) >> 16;
    hi = (unsigned short)r;
    float fh = __builtin_bit_cast(float, r << 16);
    float d = x - fh;
    unsigned u2 = __builtin_bit_cast(unsigned, d);
    unsigned r2 = (u2 + 0x7FFFu + ((u2 >> 16) & 1u)) >> 16;
    lo = (unsigned short)r2;
}

// ---------------------------------------------------------------------------
// K0: convert W[e][h] fp32 -> fragment-ordered bf16 hi/lo.
// Frag order: for K-step s (32 e), h-group g (16 h): lane l = ((e>>3)&3)*16 + (h&15)
// needs 8 consecutive e (j = e&7). Flat index = (s*16+g)*512 + l*8 + j.
// Then proj's B-frag load is a fully-coalesced global_load_dwordx4 at +l*16B.
// ---------------------------------------------------------------------------
__global__ __launch_bounds__(256) void wconv_kernel(
    const float* __restrict__ We, const float* __restrict__ Wd,
    unsigned short* __restrict__ WtEh, unsigned short* __restrict__ WtEl,
    unsigned short* __restrict__ WtDh, unsigned short* __restrict__ WtDl)
{
    const int blk = blockIdx.x;          // 0..1023
    const float* W; unsigned short *oh, *ol; int e;
    if (blk < 512) { W = We; oh = WtEh; ol = WtEl; e = blk; }
    else           { W = Wd; oh = WtDh; ol = WtDl; e = blk - 512; }
    const int h = threadIdx.x;           // 0..255
    float x = W[(size_t)e * H_ + h];
    unsigned short hi, lo; bf16split(x, hi, lo);
    const int s = e >> 5, q = (e >> 3) & 3, j = e & 7;
    const int g = h >> 4, r = h & 15, l = q * 16 + r;
    const size_t idx = (size_t)(s * 16 + g) * 512 + l * 8 + j;
    oh[idx] = hi; ol[idx] = lo;
}

// ---------------------------------------------------------------------------
// K1 v5: MFMA projection + exp2. Grid 476:
//   blk 0..399 : enc -> chunk = blk>>1 (16 rows), hh = blk&1 (128-h half)
//   blk 400..475: dec -> chunk = (blk-400)>>1, hh = (blk-400)&1
// bf16 hi/lo 3-pass emulation of fp32 GEMM on v_mfma_f32_16x16x32_bf16.
// A tile (16 rows x 512 e) staged once in LDS as hi/lo, chunk-XOR swizzled.
// B frags read straight from fragment-ordered global (coalesced 16B/lane).
// Epilogue: out[row,h] = exp2( c * (acc + bias[h]) ).
// ---------------------------------------------------------------------------
__global__ __launch_bounds__(256) void proj_mfma_kernel(
    const float* __restrict__ enc, const float* __restrict__ dec,
    const unsigned short* __restrict__ WtEh, const unsigned short* __restrict__ WtEl,
    const unsigned short* __restrict__ WtDh, const unsigned short* __restrict__ WtDl,
    const float* __restrict__ b_enc, const float* __restrict__ b_dec,
    float* __restrict__ Ee, float* __restrict__ Ed)
{
    const int tid = threadIdx.x;
    int blk = blockIdx.x;
    const float* in; const unsigned short *Wh, *Wl; const float* bias; float* outp;
    int rmax;
    if (blk < 400) { in = enc; Wh = WtEh; Wl = WtEl; bias = b_enc; outp = Ee; rmax = B_ * T_ - 1; }
    else { blk -= 400; in = dec; Wh = WtDh; Wl = WtDl; bias = b_dec; outp = Ed; rmax = B_ * U_ - 1; }
    const int hh   = blk & 1;
    const int row0 = (blk >> 1) * 16;

    __shared__ unsigned short Ah[16 * 512];
    __shared__ unsigned short Al[16 * 512];

    // ---- stage A tile: 16 rows x 512 e -> bf16 hi/lo, XOR-swizzled 16B chunks
    #pragma unroll
    for (int k = 0; k < 4; ++k) {
        const int chunk = tid + 256 * k;        // 0..1023
        const int r = chunk >> 6;               // row 0..15
        const int c = chunk & 63;               // 8-e chunk 0..63
        int gr = row0 + r; if (gr > rmax) gr = rmax;
        const float* src = in + (size_t)gr * D_ + c * 8;
        const float4 f0 = ((const float4*)src)[0];
        const float4 f1 = ((const float4*)src)[1];
        float v[8] = {f0.x, f0.y, f0.z, f0.w, f1.x, f1.y, f1.z, f1.w};
        bf16x8 ah, al;
        #pragma unroll
        for (int j = 0; j < 8; ++j) {
            unsigned short hi, lo; bf16split(v[j], hi, lo);
            ah[j] = (short)hi; al[j] = (short)lo;
        }
        const int di = r * 512 + ((c ^ (r & 7)) << 3);
        *(bf16x8*)&Ah[di] = ah;
        *(bf16x8*)&Al[di] = al;
    }
    __syncthreads();

    const int lane = tid & 63, w = tid >> 6;    // wave 0..3 -> 32-h slice
    const int q = lane >> 4, r15 = lane & 15;

    f32x4 acc0 = {0.f, 0.f, 0.f, 0.f};
    f32x4 acc1 = {0.f, 0.f, 0.f, 0.f};

    // B-frag base: group g = 8*hh + 2*w + nt ; offset (s*16+g)*512 + lane*8
    const unsigned short* bh0 = Wh + (size_t)(8 * hh + 2 * w) * 512 + lane * 8;
    const unsigned short* bl0 = Wl + (size_t)(8 * hh + 2 * w) * 512 + lane * 8;

    #pragma unroll 4
    for (int s = 0; s < 16; ++s) {
        const int ai = r15 * 512 + ((((s << 2) + q) ^ (r15 & 7)) << 3);
        const bf16x8 ahf = *(const bf16x8*)&Ah[ai];
        const bf16x8 alf = *(const bf16x8*)&Al[ai];
        const size_t so = (size_t)(s * 16) * 512;
        const bf16x8 bh_0 = *(const bf16x8*)(bh0 + so);
        const bf16x8 bl_0 = *(const bf16x8*)(bl0 + so);
        const bf16x8 bh_1 = *(const bf16x8*)(bh0 + so + 512);
        const bf16x8 bl_1 = *(const bf16x8*)(bl0 + so + 512);
        acc0 = __builtin_amdgcn_mfma_f32_16x16x32_bf16(ahf, bh_0, acc0, 0, 0, 0);
        acc0 = __builtin_amdgcn_mfma_f32_16x16x32_bf16(ahf, bl_0, acc0, 0, 0, 0);
        acc0 = __builtin_amdgcn_mfma_f32_16x16x32_bf16(alf, bh_0, acc0, 0, 0, 0);
        acc1 = __builtin_amdgcn_mfma_f32_16x16x32_bf16(ahf, bh_1, acc1, 0, 0, 0);
        acc1 = __builtin_amdgcn_mfma_f32_16x16x32_bf16(ahf, bl_1, acc1, 0, 0, 0);
        acc1 = __builtin_amdgcn_mfma_f32_16x16x32_bf16(alf, bh_1, acc1, 0, 0, 0);
    }

    // ---- epilogue: D[m][n]: m = 4q+reg (row), n = r15 (h within 16-group)
    #pragma unroll
    for (int nt = 0; nt < 2; ++nt) {
        const int h = 128 * hh + 32 * w + nt * 16 + r15;
        const float bv = bias[h];
        const f32x4 a = nt ? acc1 : acc0;
        #pragma unroll
        for (int reg = 0; reg < 4; ++reg) {
            const int trow = row0 + 4 * q + reg;
            if (trow <= rmax)
                outp[(size_t)trow * H_ + h] = fast_exp2(ARG_SCALE * (a[reg] + bv));
        }
    }
}

// ---------------------------------------------------------------------------
// K2 v4 (unchanged): partial scores via exp-product. 128 threads; 32t x 32u
// tile; thread owns 4t x 2u. Grid (x: ut 0..4 | hs 0..1, y: tt, z: b).
//   sig = rcp(fma(Ee, Ed, 1))  ->  2 VALU / 1 trans per element
// ---------------------------------------------------------------------------
__global__ __launch_bounds__(128) void score_kernel(
    const float* __restrict__ Ee, const float* __restrict__ Ed,
    const float* __restrict__ w_score,
    float* __restrict__ sc0, float* __restrict__ sc1)
{
    const int tid = threadIdx.x;
    const int ut = blockIdx.x % 5, hs = blockIdx.x / 5;
    const int tt = blockIdx.y, b = blockIdx.z;

    __shared__ float eld[32][PADH2];
    __shared__ float dld[32][PADH2];

    const int t0 = tt * 32, u0 = ut * 32;
    const int hoff = hs * 128;

    #pragma unroll
    for (int k = 0; k < 8; ++k) {
        int idx = tid + 128 * k;    // 0..1023
        int row = idx >> 5;         // 0..31
        int f4  = idx & 31;         // float4 index within the 128-h half
        *(float4*)&eld[row][4 * f4] =
            *(const float4*)(Ee + (size_t)(b * T_ + t0 + row) * H_ + hoff + 4 * f4);
        int du = u0 + row; if (du > U_ - 1) du = U_ - 1;
        *(float4*)&dld[row][4 * f4] =
            *(const float4*)(Ed + (size_t)(b * U_ + du) * H_ + hoff + 4 * f4);
    }
    __syncthreads();

    const int tx = tid & 15, ty = tid >> 4;       // ty 0..7
    const float* e0 = &eld[4 * ty + 0][0];
    const float* e1 = &eld[4 * ty + 1][0];
    const float* e2 = &eld[4 * ty + 2][0];
    const float* e3 = &eld[4 * ty + 3][0];
    const float* d0 = &dld[tx][0];
    const float* d1 = &dld[tx + 16][0];
    const float* wp = w_score + hoff;             // uniform -> s_load

    float4 z4 = {0.f, 0.f, 0.f, 0.f};
    float4 a00 = z4, a01 = z4, a10 = z4, a11 = z4;
    float4 a20 = z4, a21 = z4, a30 = z4, a31 = z4;

#define SIG(E, D) fast_rcp(fmaf((E), (D), 1.f))
#define ROW(A, EV, DV) \
    A.x = fmaf(w.x, SIG(EV.x, DV.x), A.x); \
    A.y = fmaf(w.y, SIG(EV.y, DV.y), A.y); \
    A.z = fmaf(w.z, SIG(EV.z, DV.z), A.z); \
    A.w = fmaf(w.w, SIG(EV.w, DV.w), A.w);

    #pragma unroll 4
    for (int h4 = 0; h4 < 32; ++h4) {
        float4 w  = ((const float4*)wp)[h4];
        float4 ea = *(const float4*)(e0 + 4 * h4);
        float4 eb = *(const float4*)(e1 + 4 * h4);
        float4 ec = *(const float4*)(e2 + 4 * h4);
        float4 ed = *(const float4*)(e3 + 4 * h4);
        float4 da = *(const float4*)(d0 + 4 * h4);
        float4 db = *(const float4*)(d1 + 4 * h4);
        ROW(a00, ea, da) ROW(a01, ea, db)
        ROW(a10, eb, da) ROW(a11, eb, db)
        ROW(a20, ec, da) ROW(a21, ec, db)
        ROW(a30, ed, da) ROW(a31, ed, db)
    }
#undef ROW
#undef SIG

    float s0[4], s1[4];
    s0[0] = (a00.x + a00.y) + (a00.z + a00.w);
    s0[1] = (a10.x + a10.y) + (a10.z + a10.w);
    s0[2] = (a20.x + a20.y) + (a20.z + a20.w);
    s0[3] = (a30.x + a30.y) + (a30.z + a30.w);
    s1[0] = (a01.x + a01.y) + (a01.z + a01.w);
    s1[1] = (a11.x + a11.y) + (a11.z + a11.w);
    s1[2] = (a21.x + a21.y) + (a21.z + a21.w);
    s1[3] = (a31.x + a31.y) + (a31.z + a31.w);

    float* sout = hs ? sc1 : sc0;
    const int ua = u0 + tx, ub = ua + 16;
    #pragma unroll
    for (int j = 0; j < 4; ++j) {
        const int t = t0 + 4 * ty + j;
        const size_t base = (size_t)(b * T_ + t) * U_;
        sout[base + ua] = s0[j];
        if (ub < U_) sout[base + ub] = s1[j];
    }
}

// ---------------------------------------------------------------------------
// K3 (unchanged): softmax over U=150 of z = -2*(sc0+sc1). One wave per row.
// ---------------------------------------------------------------------------
__global__ __launch_bounds__(256) void softmax_kernel(
    const float* __restrict__ sc0, const float* __restrict__ sc1,
    float* __restrict__ out)
{
    const int tid  = threadIdx.x;
    const int wave = tid >> 6, lane = tid & 63;
    const int row  = blockIdx.x * 4 + wave;       // 0..3199
    const size_t base = (size_t)row * U_;

    float z0 = -2.f * (sc0[base + lane]      + sc1[base + lane]);
    float z1 = -2.f * (sc0[base + lane + 64] + sc1[base + lane + 64]);
    const bool v2 = (lane + 128) < U_;
    float z2 = v2 ? -2.f * (sc0[base + lane + 128] + sc1[base + lane + 128])
                  : -INFINITY;

    float m = fmaxf(fmaxf(z0, z1), z2);
    #pragma unroll
    for (int off = 32; off > 0; off >>= 1) m = fmaxf(m, __shfl_xor(m, off));

    float p0 = fast_exp2((z0 - m) * LOG2E_F);
    float p1 = fast_exp2((z1 - m) * LOG2E_F);
    float p2 = v2 ? fast_exp2((z2 - m) * LOG2E_F) : 0.f;

    float s = p0 + p1 + p2;
    #pragma unroll
    for (int off = 32; off > 0; off >>= 1) s += __shfl_xor(s, off);

    const float inv = 1.0f / s;
    out[base + lane]      = p0 * inv;
    out[base + lane + 64] = p1 * inv;
    if (v2) out[base + lane + 128] = p2 * inv;
}

// ---------------------------------------------------------------------------
extern "C" void kernel_launch(void* const* d_in, const int* in_sizes, int n_in,
                              void* d_out, int out_size, void* d_ws, size_t ws_size,
                              hipStream_t stream) {
    const float* enc     = (const float*)d_in[0];
    const float* dec     = (const float*)d_in[1];
    const float* W_enc   = (const float*)d_in[2];
    const float* b_enc   = (const float*)d_in[3];
    const float* W_dec   = (const float*)d_in[4];
    const float* b_dec   = (const float*)d_in[5];
    const float* w_score = (const float*)d_in[6];
    // d_in[7] = b_score: cancels in softmax, unused.

    float* ws = (float*)d_ws;
    float* Ee  = ws;                    // [3200,256] exp2(c*enc_proj)
    float* Ed  = Ee + 819200;           // [600,256]
    float* sc0 = Ed + 153600;           // [3200,150] partial score h 0..127
    float* sc1 = sc0 + 480000;          // [3200,150] partial score h 128..255
    unsigned short* WtEh = (unsigned short*)(sc1 + 480000);  // 131072 each
    unsigned short* WtEl = WtEh + 131072;
    unsigned short* WtDh = WtEl + 131072;
    unsigned short* WtDl = WtDh + 131072;
    float* out = (float*)d_out;

    wconv_kernel<<<1024, 256, 0, stream>>>(W_enc, W_dec, WtEh, WtEl, WtDh, WtDl);
    proj_mfma_kernel<<<476, 256, 0, stream>>>(enc, dec, WtEh, WtEl, WtDh, WtDl,
                                              b_enc, b_dec, Ee, Ed);
    score_kernel<<<dim3(10, 25, 4), 128, 0, stream>>>(Ee, Ed, w_score, sc0, sc1);
    softmax_kernel<<<800, 256, 0, stream>>>(sc0, sc1, out);
}

// Round 6
// 41.512 us; speedup vs baseline: 1.0723x; 1.0723x over previous
//
#include <hip/hip_runtime.h>
#include <hip/hip_bf16.h>

#define B_ 4
#define T_ 800
#define U_ 150
#define D_ 512
#define H_ 256
#define PADH2 132   // 132 % 32 == 4 -> worst LDS aliasing 2-way (free)

static constexpr float ARG_SCALE = 2.8853900817779268f; // 2/ln2: tanh(x)=1-2/(1+2^(c*x))
static constexpr float LOG2E_F   = 1.4426950408889634f;

typedef __attribute__((ext_vector_type(8))) short bf16x8;   // 8 bf16 in 4 VGPRs
typedef __attribute__((ext_vector_type(4))) float f32x4;

extern "C" __device__ float __ocml_exp2_f32(float);

__device__ __forceinline__ float fast_exp2(float x) {
#if __has_builtin(__builtin_amdgcn_exp2f)
    return __builtin_amdgcn_exp2f(x);
#else
    return __ocml_exp2_f32(x);
#endif
}
__device__ __forceinline__ float fast_rcp(float x) {
#if __has_builtin(__builtin_amdgcn_rcpf)
    return __builtin_amdgcn_rcpf(x);
#else
    return 1.0f / x;
#endif
}

// round-to-nearest-even fp32 -> bf16 hi, residual lo
__device__ __forceinline__ void bf16split(float x, unsigned short& hi, unsigned short& lo) {
    unsigned u = __builtin_bit_cast(unsigned, x);
    unsigned r = (u + 0x7FFFu + ((u >> 16) & 1u)) >> 16;
    hi = (unsigned short)r;
    float fh = __builtin_bit_cast(float, r << 16);
    float d = x - fh;
    unsigned u2 = __builtin_bit_cast(unsigned, d);
    unsigned r2 = (u2 + 0x7FFFu + ((u2 >> 16) & 1u)) >> 16;
    lo = (unsigned short)r2;
}

// ---------------------------------------------------------------------------
// K0: convert c*W[e][h] fp32 -> fragment-ordered bf16 hi/lo (c = ARG_SCALE).
// Frag order: K-step s (32 e), h-group g (16 h), lane l = ((e>>3)&3)*16+(h&15),
// j = e&7. Flat index = (s*16+g)*512 + l*8 + j  -> proj B-load is coalesced 16B.
// ---------------------------------------------------------------------------
__global__ __launch_bounds__(256) void wconv_kernel(
    const float* __restrict__ We, const float* __restrict__ Wd,
    unsigned short* __restrict__ WtEh, unsigned short* __restrict__ WtEl,
    unsigned short* __restrict__ WtDh, unsigned short* __restrict__ WtDl)
{
    const int blk = blockIdx.x;          // 0..1023
    const float* W; unsigned short *oh, *ol; int e;
    if (blk < 512) { W = We; oh = WtEh; ol = WtEl; e = blk; }
    else           { W = Wd; oh = WtDh; ol = WtDl; e = blk - 512; }
    const int h = threadIdx.x;           // 0..255
    float x = ARG_SCALE * W[(size_t)e * H_ + h];
    unsigned short hi, lo; bf16split(x, hi, lo);
    const int s = e >> 5, q = (e >> 3) & 3, j = e & 7;
    const int g = h >> 4, r = h & 15, l = q * 16 + r;
    const size_t idx = (size_t)(s * 16 + g) * 512 + l * 8 + j;
    oh[idx] = hi; ol[idx] = lo;
}

// ---------------------------------------------------------------------------
// K1 v6: MFMA projection + exp2. Grid 952:
//   blk 0..799 : enc -> chunk = blk>>2 (16 rows), hq = blk&3 (64-h quarter)
//   blk 800..951: dec -> chunk = (blk-800)>>2 (38 chunks, ragged), hq likewise
// Wave w handles h-group g = 4*hq + w (16 h). 48 MFMA per wave (hi/lo 3-pass).
// A tile (16 rows x 512 e) staged in LDS as bf16 hi/lo, chunk-XOR swizzled.
// Epilogue: out[row,h] = exp2( acc + c*bias[h] )   (c folded into W by wconv)
// ---------------------------------------------------------------------------
__global__ __launch_bounds__(256) void proj_mfma_kernel(
    const float* __restrict__ enc, const float* __restrict__ dec,
    const unsigned short* __restrict__ WtEh, const unsigned short* __restrict__ WtEl,
    const unsigned short* __restrict__ WtDh, const unsigned short* __restrict__ WtDl,
    const float* __restrict__ b_enc, const float* __restrict__ b_dec,
    float* __restrict__ Ee, float* __restrict__ Ed)
{
    const int tid = threadIdx.x;
    int blk = blockIdx.x;
    const float* in; const unsigned short *Wh, *Wl; const float* bias; float* outp;
    int rmax;
    if (blk < 800) { in = enc; Wh = WtEh; Wl = WtEl; bias = b_enc; outp = Ee; rmax = B_ * T_ - 1; }
    else { blk -= 800; in = dec; Wh = WtDh; Wl = WtDl; bias = b_dec; outp = Ed; rmax = B_ * U_ - 1; }
    const int hq   = blk & 3;
    const int row0 = (blk >> 2) * 16;

    __shared__ unsigned short Ah[16 * 512];
    __shared__ unsigned short Al[16 * 512];

    // ---- stage A tile: 16 rows x 512 e -> bf16 hi/lo, XOR-swizzled 16B chunks
    #pragma unroll
    for (int k = 0; k < 4; ++k) {
        const int chunk = tid + 256 * k;        // 0..1023
        const int r = chunk >> 6;               // row 0..15
        const int c = chunk & 63;               // 8-e chunk 0..63
        int gr = row0 + r; if (gr > rmax) gr = rmax;
        const float* src = in + (size_t)gr * D_ + c * 8;
        const float4 f0 = ((const float4*)src)[0];
        const float4 f1 = ((const float4*)src)[1];
        float v[8] = {f0.x, f0.y, f0.z, f0.w, f1.x, f1.y, f1.z, f1.w};
        bf16x8 ah, al;
        #pragma unroll
        for (int j = 0; j < 8; ++j) {
            unsigned short hi, lo; bf16split(v[j], hi, lo);
            ah[j] = (short)hi; al[j] = (short)lo;
        }
        const int di = r * 512 + ((c ^ (r & 7)) << 3);
        *(bf16x8*)&Ah[di] = ah;
        *(bf16x8*)&Al[di] = al;
    }
    __syncthreads();

    const int lane = tid & 63, w = tid >> 6;
    const int q = lane >> 4, r15 = lane & 15;
    const int g = 4 * hq + w;                   // h-group 0..15

    f32x4 acc = {0.f, 0.f, 0.f, 0.f};
    const unsigned short* bh0 = Wh + (size_t)g * 512 + lane * 8;
    const unsigned short* bl0 = Wl + (size_t)g * 512 + lane * 8;

    #pragma unroll 4
    for (int s = 0; s < 16; ++s) {
        const int ai = r15 * 512 + ((((s << 2) + q) ^ (r15 & 7)) << 3);
        const bf16x8 ahf = *(const bf16x8*)&Ah[ai];
        const bf16x8 alf = *(const bf16x8*)&Al[ai];
        const size_t so = (size_t)(s * 16) * 512;
        const bf16x8 bh = *(const bf16x8*)(bh0 + so);
        const bf16x8 bl = *(const bf16x8*)(bl0 + so);
        acc = __builtin_amdgcn_mfma_f32_16x16x32_bf16(ahf, bh, acc, 0, 0, 0);
        acc = __builtin_amdgcn_mfma_f32_16x16x32_bf16(ahf, bl, acc, 0, 0, 0);
        acc = __builtin_amdgcn_mfma_f32_16x16x32_bf16(alf, bh, acc, 0, 0, 0);
    }

    // ---- epilogue: D[m][n]: m = 4q+reg (row), n = r15 -> h = g*16 + r15
    const int h = g * 16 + r15;
    const float bv = bias[h];
    #pragma unroll
    for (int reg = 0; reg < 4; ++reg) {
        const int trow = row0 + 4 * q + reg;
        if (trow <= rmax)
            outp[(size_t)trow * H_ + h] = fast_exp2(fmaf(ARG_SCALE, bv, acc[reg]));
    }
}

// ---------------------------------------------------------------------------
// K2 v5: partial scores, one rcp per 4 h-elements (exact algebra):
//   t_i = fma(Ee_i, Ed_i, 1)            (the 1+exp factors, all >= 1)
//   Dab = t0*t1, Nab = w0*t1 + w1*t0 ;  Dcd, Ncd likewise
//   quad = (Nab*Dcd + Ncd*Dab) / (Dab*Dcd)   -> 14 VALU + 1 rcp / 4 elems
// 128 threads; 32t x 32u tile; thread owns 4t x 2u. Grid (ut|hs, tt, b).
// ---------------------------------------------------------------------------
__global__ __launch_bounds__(128) void score_kernel(
    const float* __restrict__ Ee, const float* __restrict__ Ed,
    const float* __restrict__ w_score,
    float* __restrict__ sc0, float* __restrict__ sc1)
{
    const int tid = threadIdx.x;
    const int ut = blockIdx.x % 5, hs = blockIdx.x / 5;
    const int tt = blockIdx.y, b = blockIdx.z;

    __shared__ float eld[32][PADH2];
    __shared__ float dld[32][PADH2];

    const int t0 = tt * 32, u0 = ut * 32;
    const int hoff = hs * 128;

    #pragma unroll
    for (int k = 0; k < 8; ++k) {
        int idx = tid + 128 * k;    // 0..1023
        int row = idx >> 5;         // 0..31
        int f4  = idx & 31;         // float4 index within the 128-h half
        *(float4*)&eld[row][4 * f4] =
            *(const float4*)(Ee + (size_t)(b * T_ + t0 + row) * H_ + hoff + 4 * f4);
        int du = u0 + row; if (du > U_ - 1) du = U_ - 1;
        *(float4*)&dld[row][4 * f4] =
            *(const float4*)(Ed + (size_t)(b * U_ + du) * H_ + hoff + 4 * f4);
    }
    __syncthreads();

    const int tx = tid & 15, ty = tid >> 4;       // ty 0..7
    const float* e0 = &eld[4 * ty + 0][0];
    const float* e1 = &eld[4 * ty + 1][0];
    const float* e2 = &eld[4 * ty + 2][0];
    const float* e3 = &eld[4 * ty + 3][0];
    const float* d0 = &dld[tx][0];
    const float* d1 = &dld[tx + 16][0];
    const float* wp = w_score + hoff;             // uniform -> s_load

    float a00 = 0.f, a01 = 0.f, a10 = 0.f, a11 = 0.f;
    float a20 = 0.f, a21 = 0.f, a30 = 0.f, a31 = 0.f;

#define QUAD(EV, DV, A) { \
    float q0 = fmaf(EV.x, DV.x, 1.f); \
    float q1 = fmaf(EV.y, DV.y, 1.f); \
    float q2 = fmaf(EV.z, DV.z, 1.f); \
    float q3 = fmaf(EV.w, DV.w, 1.f); \
    float Dab = q0 * q1, Dcd = q2 * q3; \
    float Nab = fmaf(w.x, q1, w.y * q0); \
    float Ncd = fmaf(w.z, q3, w.w * q2); \
    float N = fmaf(Nab, Dcd, Ncd * Dab); \
    A = fmaf(N, fast_rcp(Dab * Dcd), A); }

    #pragma unroll 4
    for (int h4 = 0; h4 < 32; ++h4) {
        float4 w  = ((const float4*)wp)[h4];
        float4 ea = *(const float4*)(e0 + 4 * h4);
        float4 eb = *(const float4*)(e1 + 4 * h4);
        float4 ec = *(const float4*)(e2 + 4 * h4);
        float4 ed = *(const float4*)(e3 + 4 * h4);
        float4 da = *(const float4*)(d0 + 4 * h4);
        float4 db = *(const float4*)(d1 + 4 * h4);
        QUAD(ea, da, a00) QUAD(ea, db, a01)
        QUAD(eb, da, a10) QUAD(eb, db, a11)
        QUAD(ec, da, a20) QUAD(ec, db, a21)
        QUAD(ed, da, a30) QUAD(ed, db, a31)
    }
#undef QUAD

    float s0[4] = {a00, a10, a20, a30};
    float s1[4] = {a01, a11, a21, a31};

    float* sout = hs ? sc1 : sc0;
    const int ua = u0 + tx, ub = ua + 16;
    #pragma unroll
    for (int j = 0; j < 4; ++j) {
        const int t = t0 + 4 * ty + j;
        const size_t base = (size_t)(b * T_ + t) * U_;
        sout[base + ua] = s0[j];
        if (ub < U_) sout[base + ub] = s1[j];
    }
}

// ---------------------------------------------------------------------------
// K3 (unchanged): softmax over U=150 of z = -2*(sc0+sc1). One wave per row.
// ---------------------------------------------------------------------------
__global__ __launch_bounds__(256) void softmax_kernel(
    const float* __restrict__ sc0, const float* __restrict__ sc1,
    float* __restrict__ out)
{
    const int tid  = threadIdx.x;
    const int wave = tid >> 6, lane = tid & 63;
    const int row  = blockIdx.x * 4 + wave;       // 0..3199
    const size_t base = (size_t)row * U_;

    float z0 = -2.f * (sc0[base + lane]      + sc1[base + lane]);
    float z1 = -2.f * (sc0[base + lane + 64] + sc1[base + lane + 64]);
    const bool v2 = (lane + 128) < U_;
    float z2 = v2 ? -2.f * (sc0[base + lane + 128] + sc1[base + lane + 128])
                  : -INFINITY;

    float m = fmaxf(fmaxf(z0, z1), z2);
    #pragma unroll
    for (int off = 32; off > 0; off >>= 1) m = fmaxf(m, __shfl_xor(m, off));

    float p0 = fast_exp2((z0 - m) * LOG2E_F);
    float p1 = fast_exp2((z1 - m) * LOG2E_F);
    float p2 = v2 ? fast_exp2((z2 - m) * LOG2E_F) : 0.f;

    float s = p0 + p1 + p2;
    #pragma unroll
    for (int off = 32; off > 0; off >>= 1) s += __shfl_xor(s, off);

    const float inv = 1.0f / s;
    out[base + lane]      = p0 * inv;
    out[base + lane + 64] = p1 * inv;
    if (v2) out[base + lane + 128] = p2 * inv;
}

// ---------------------------------------------------------------------------
extern "C" void kernel_launch(void* const* d_in, const int* in_sizes, int n_in,
                              void* d_out, int out_size, void* d_ws, size_t ws_size,
                              hipStream_t stream) {
    const float* enc     = (const float*)d_in[0];
    const float* dec     = (const float*)d_in[1];
    const float* W_enc   = (const float*)d_in[2];
    const float* b_enc   = (const float*)d_in[3];
    const float* W_dec   = (const float*)d_in[4];
    const float* b_dec   = (const float*)d_in[5];
    const float* w_score = (const float*)d_in[6];
    // d_in[7] = b_score: cancels in softmax, unused.

    float* ws = (float*)d_ws;
    float* Ee  = ws;                    // [3200,256] exp2(c*enc_proj)
    float* Ed  = Ee + 819200;           // [600,256]
    float* sc0 = Ed + 153600;           // [3200,150] partial score h 0..127
    float* sc1 = sc0 + 480000;          // [3200,150] partial score h 128..255
    unsigned short* WtEh = (unsigned short*)(sc1 + 480000);  // 131072 each
    unsigned short* WtEl = WtEh + 131072;
    unsigned short* WtDh = WtEl + 131072;
    unsigned short* WtDl = WtDh + 131072;
    float* out = (float*)d_out;

    wconv_kernel<<<1024, 256, 0, stream>>>(W_enc, W_dec, WtEh, WtEl, WtDh, WtDl);
    proj_mfma_kernel<<<952, 256, 0, stream>>>(enc, dec, WtEh, WtEl, WtDh, WtDl,
                                              b_enc, b_dec, Ee, Ed);
    score_kernel<<<dim3(10, 25, 4), 128, 0, stream>>>(Ee, Ed, w_score, sc0, sc1);
    softmax_kernel<<<800, 256, 0, stream>>>(sc0, sc1, out);
}